// Round 14
// baseline (2256.832 us; speedup 1.0000x reference)
//
#include <hip/hip_runtime.h>
#include <stdint.h>

typedef unsigned short u16;
typedef unsigned int u32;
typedef unsigned char u8;

typedef __attribute__((ext_vector_type(4))) float f32x4;
typedef __attribute__((ext_vector_type(4))) u32 u32x4;
typedef __attribute__((ext_vector_type(8))) __bf16 bf16x8;

#define NITER 48
#define TT 512
#define BB 128
#define ASTART 6   // buckets >= ASTART run in the single flag-sync dispatch

__device__ __forceinline__ u16 f2bf(float f){
    u32 u = __builtin_bit_cast(u32, f);
    u = (u + 0x7FFFu + ((u >> 16) & 1u)) >> 16;
    return (u16)u;
}
__device__ __forceinline__ float bf2f(u16 v){
    u32 u = ((u32)v) << 16;
    return __builtin_bit_cast(float, u);
}
__device__ __forceinline__ u32x4 pack8(f32x4 a, f32x4 b){
    u32x4 u;
    u[0] = (u32)f2bf(a[0]) | ((u32)f2bf(a[1]) << 16);
    u[1] = (u32)f2bf(a[2]) | ((u32)f2bf(a[3]) << 16);
    u[2] = (u32)f2bf(b[0]) | ((u32)f2bf(b[1]) << 16);
    u[3] = (u32)f2bf(b[2]) | ((u32)f2bf(b[3]) << 16);
    return u;
}
__device__ __forceinline__ void glds16(const u16* g, u16* l){
    __builtin_amdgcn_global_load_lds(
        (const __attribute__((address_space(1))) u32*)g,
        (__attribute__((address_space(3))) u32*)l, 16, 0, 0);
}

// ---------- resets dtype detection ----------
__global__ void k_detect(const u8* __restrict__ r, int* __restrict__ flag){
    __shared__ int nz[4];
    if (threadIdx.x < 4) nz[threadIdx.x] = 0;
    __syncthreads();
    int loc[4] = {0,0,0,0};
    const int base = threadIdx.x * 16;
    #pragma unroll
    for (int i = 0; i < 16; ++i) if (r[base + i]) loc[i & 3] = 1;
    #pragma unroll
    for (int j = 0; j < 4; ++j) if (loc[j]) atomicOr(&nz[j], 1);
    __syncthreads();
    if (threadIdx.x == 0){
        int f;
        if (nz[0] && !nz[1] && !nz[2] && !nz[3]) f = 0;
        else if (!nz[0] && !nz[1] && (nz[2] || nz[3])) f = 2;
        else f = 1;
        *flag = f;
    }
}

__device__ __forceinline__ int reset_at(const void* r, int f, int idx){
    if (f == 0) return ((const int*)r)[idx] != 0;
    if (f == 1) return ((const u8*)r)[idx] != 0;
    return ((const float*)r)[idx] != 0.f;
}

// ---------- ages + per-block histogram (deterministic) ----------
__global__ void k_ages(const void* __restrict__ resets, const int* __restrict__ flag,
                       int b0, int bw_log, u8* __restrict__ age, int* __restrict__ bh){
    __shared__ int lc[NITER];
    const int tid = threadIdx.x;
    if (tid < NITER) lc[tid] = 0;
    __syncthreads();
    const int cid = blockIdx.x * 256 + tid;
    const int f = *flag;
    const int bwm = (1 << bw_log) - 1;
    const int t = cid >> bw_log, b = b0 + (cid & bwm);
    int a = 0, tt = t;
    while (tt > 0 && !reset_at(resets, f, tt * BB + b)){ ++a; --tt; }
    if (a > NITER - 1) a = NITER - 1;
    age[cid] = (u8)a;
    atomicAdd(&lc[a], 1);
    __syncthreads();
    if (tid < NITER) bh[blockIdx.x * NITER + tid] = lc[tid];
}

// ---------- offsets + per-block bases + group/tile bases ----------
__global__ void k_offsets(const int* __restrict__ bh, int NB,
                          int* __restrict__ counts, int* __restrict__ offs,
                          int* __restrict__ gbase, int* __restrict__ tbase,
                          int* __restrict__ bb){
    const int a = threadIdx.x;
    if (a < NITER){
        int run = 0;
        for (int b = 0; b < NB; ++b){
            bb[b * NITER + a] = run;
            run += bh[b * NITER + a];
        }
        counts[a] = run;
    }
    __syncthreads();
    if (a == 0){
        int o = 0;
        for (int i = 0; i < NITER; ++i){ offs[i] = o; o += counts[i]; }
        offs[NITER] = o;
        int g = 0, t = 0;
        for (int i = 0; i < NITER; ++i){
            const int ng = (counts[i] + 127) >> 7;
            gbase[i] = g; g += ng;
            tbase[i] = t; t += (i == 0) ? ng : ng * 16;
        }
        gbase[NITER] = g;
        tbase[NITER] = t;
    }
}

// ---------- stable scatter: bucket-internal order == cid order (chain order) ----------
__global__ void k_scatter(const u8* __restrict__ age, const int* __restrict__ offs,
                          const int* __restrict__ bb,
                          u16* __restrict__ list, u16* __restrict__ posof){
    __shared__ u8 sa[256];
    const int tid = threadIdx.x;
    const int cid = blockIdx.x * 256 + tid;
    const int a = age[cid];
    sa[tid] = (u8)a;
    __syncthreads();
    int rank = 0;
    for (int j = 0; j < tid; ++j) rank += (sa[j] == (u8)a);
    const int pos = offs[a] + bb[blockIdx.x * NITER + a] + rank;
    list[pos] = (u16)cid;
    posof[cid] = (u16)pos;
}

// ---------- weight pack: Wt[n][k] = bf16(W[k][n]) ----------
__global__ void k_packT(const float* __restrict__ Wi, const float* __restrict__ Wh,
                        u16* __restrict__ Wit, u16* __restrict__ Wht){
    __shared__ float tl[32][33];
    const int kb = blockIdx.x * 32;
    const int nb = blockIdx.y * 32;
    const float* W = blockIdx.z ? Wh : Wi;
    u16* Wt = blockIdx.z ? Wht : Wit;
    const int tx = threadIdx.x;
    for (int r = threadIdx.y; r < 32; r += 8)
        tl[r][tx] = W[(size_t)(kb + r) * 3072 + nb + tx];
    __syncthreads();
    for (int r = threadIdx.y; r < 32; r += 8)
        Wt[(size_t)(nb + r) * 1024 + kb + tx] = f2bf(tl[tx][r]);
}

// ---------- fp32 -> bf16 input conversion (nt loads: ins is read exactly once) ----------
__global__ void k_tobf(const float* __restrict__ ins, u16* __restrict__ insbf,
                       int b0, int bw_log, int total8){
    const int bwm = (1 << bw_log) - 1;
    for (int i = blockIdx.x * 256 + threadIdx.x; i < total8; i += gridDim.x * 256){
        const int cid = i >> 7;
        const int c8 = (i & 127) * 8;
        const int t = cid >> bw_log, j = cid & bwm;
        const float* src = ins + (size_t)(t * BB + b0 + j) * 1024 + c8;
        f32x4 a = __builtin_nontemporal_load((const f32x4*)src);
        f32x4 b = __builtin_nontemporal_load((const f32x4*)(src + 4));
        *(u32x4*)(insbf + (size_t)cid * 1024 + c8) = pack8(a, b);
    }
}

// ---------- xi = insbf @ Wit^T : m97-style, LDS epilogue, nt xi stores ----------
__global__ __launch_bounds__(256, 4)
void k_xi(const u16* __restrict__ insbf, const u16* __restrict__ Wit,
          u16* __restrict__ xi, int Mrows)
{
    __shared__ __align__(16) u16 lds[2][8192];
    const int tid = threadIdx.x;
    const int lane = tid & 63;
    const int w = tid >> 6;
    const int wr = w >> 1, wc = w & 1;
    const int l15 = lane & 15;
    const int l4 = lane >> 4;

    const int nMt = Mrows >> 7;
    const int nTiles = nMt * 24;

    for (int idx = blockIdx.x; idx < nTiles; idx += gridDim.x){
        const int mt = idx / 24;
        const int cg = idx - mt * 24;
        const int m0 = mt * 128;
        const int c0 = cg * 128;

        const u16* ga0 = insbf + (size_t)(m0 + w * 16 + (lane >> 2)) * 1024 + (lane & 3) * 8;
        const u16* ga1 = ga0 + (size_t)64 * 1024;
        const u16* gb0 = Wit + (size_t)(c0 + w * 16 + (lane >> 2)) * 1024 + (lane & 3) * 8;
        const u16* gb1 = gb0 + (size_t)64 * 1024;

        f32x4 acc[4][4];
        #pragma unroll
        for (int i = 0; i < 4; ++i)
            #pragma unroll
            for (int j = 0; j < 4; ++j)
                acc[i][j] = (f32x4){0.f, 0.f, 0.f, 0.f};

        {
            u16* Lb = lds[0];
            glds16(ga0, &Lb[w * 512]);
            glds16(ga1, &Lb[2048 + w * 512]);
            glds16(gb0, &Lb[4096 + w * 512]);
            glds16(gb1, &Lb[6144 + w * 512]);
        }
        __syncthreads();

        for (int kt = 0; kt < 32; ++kt){
            if (kt < 31){
                u16* Nb = lds[(kt + 1) & 1];
                const int ko = (kt + 1) * 32;
                glds16(ga0 + ko, &Nb[w * 512]);
                glds16(ga1 + ko, &Nb[2048 + w * 512]);
                glds16(gb0 + ko, &Nb[4096 + w * 512]);
                glds16(gb1 + ko, &Nb[6144 + w * 512]);
            }
            const u16* L = lds[kt & 1];
            bf16x8 ax[4], bx[4];
            #pragma unroll
            for (int rf = 0; rf < 4; ++rf)
                ax[rf] = *(const bf16x8*)&L[(wr * 64 + rf * 16 + l15) * 32 + l4 * 8];
            #pragma unroll
            for (int cf = 0; cf < 4; ++cf)
                bx[cf] = *(const bf16x8*)&L[4096 + (wc * 64 + cf * 16 + l15) * 32 + l4 * 8];
            #pragma unroll
            for (int rf = 0; rf < 4; ++rf)
                #pragma unroll
                for (int cf = 0; cf < 4; ++cf)
                    acc[rf][cf] = __builtin_amdgcn_mfma_f32_16x16x32_bf16(
                        ax[rf], bx[cf], acc[rf][cf], 0, 0, 0);
            __syncthreads();
        }

        u16* region = ((u16*)lds) + w * 4096;
        #pragma unroll
        for (int rf = 0; rf < 4; ++rf)
            #pragma unroll
            for (int cf = 0; cf < 4; ++cf)
                #pragma unroll
                for (int m = 0; m < 4; ++m)
                    region[(rf * 16 + l4 * 4 + m) * 64 + cf * 16 + l15] = f2bf(acc[rf][cf][m]);
        #pragma unroll
        for (int rep = 0; rep < 8; ++rep){
            const int r = rep * 8 + (lane >> 3);
            const int cc = (lane & 7) * 8;
            u32x4 v = *(u32x4*)&region[r * 64 + cc];
            __builtin_nontemporal_store(v,
                (u32x4*)(xi + (size_t)(m0 + wr * 64 + r) * 3072 + c0 + wc * 64 + cc));
        }
        __syncthreads();
    }
}

// ---------- age-0 elementwise body (nt xi loads) ----------
__device__ __forceinline__ void h0_body(int row, int c8, const u16* __restrict__ list,
    const u16* __restrict__ xi, float* __restrict__ ys, u16* __restrict__ hbf,
    const float* __restrict__ bi, const float* __restrict__ bhn, int b0, int bw_log)
{
    const int bwm = (1 << bw_log) - 1;
    const int cid = list[row];
    const int p = ((cid >> bw_log) << 7) + b0 + (cid & bwm);
    const u16* xr = xi + (size_t)cid * 3072 + c8;
    u32x4 vr = __builtin_nontemporal_load((const u32x4*)xr);
    u32x4 vz = __builtin_nontemporal_load((const u32x4*)(xr + 1024));
    u32x4 vn = __builtin_nontemporal_load((const u32x4*)(xr + 2048));
    f32x4 br0 = *(const f32x4*)(bi + c8),        br1 = *(const f32x4*)(bi + c8 + 4);
    f32x4 bz0 = *(const f32x4*)(bi + 1024 + c8), bz1 = *(const f32x4*)(bi + 1024 + c8 + 4);
    f32x4 bn0 = *(const f32x4*)(bi + 2048 + c8), bn1 = *(const f32x4*)(bi + 2048 + c8 + 4);
    f32x4 bh0 = *(const f32x4*)(bhn + c8),       bh1 = *(const f32x4*)(bhn + c8 + 4);
    float out[8];
    #pragma unroll
    for (int e = 0; e < 8; ++e){
        const float xrv = bf2f((u16)(vr[e >> 1] >> ((e & 1) * 16)));
        const float xzv = bf2f((u16)(vz[e >> 1] >> ((e & 1) * 16)));
        const float xnv = bf2f((u16)(vn[e >> 1] >> ((e & 1) * 16)));
        const float brv = (e < 4) ? br0[e] : br1[e - 4];
        const float bzv = (e < 4) ? bz0[e] : bz1[e - 4];
        const float bnv = (e < 4) ? bn0[e] : bn1[e - 4];
        const float bhv = (e < 4) ? bh0[e] : bh1[e - 4];
        const float rr = 1.f / (1.f + __expf(-(xrv + brv)));
        const float zz = 1.f / (1.f + __expf(-(xzv + bzv)));
        const float nn = tanhf(xnv + bnv + rr * bhv);
        out[e] = (1.f - zz) * nn;
    }
    float* dst = ys + (size_t)p * 1024 + c8;
    f32x4 o0 = (f32x4){out[0], out[1], out[2], out[3]};
    f32x4 o1 = (f32x4){out[4], out[5], out[6], out[7]};
    *(f32x4*)dst = o0;
    *(f32x4*)(dst + 4) = o1;
    *(u32x4*)(hbf + (size_t)row * 1024 + c8) = pack8(o0, o1);
}

__global__ void k_h0(const u16* __restrict__ list, const int* __restrict__ counts,
                     const u16* __restrict__ xi, float* __restrict__ ys,
                     u16* __restrict__ hbf, const float* __restrict__ bi,
                     const float* __restrict__ bhn, int b0, int bw_log)
{
    const int total = counts[0] * 128;
    for (int i = blockIdx.x * 256 + threadIdx.x; i < total; i += gridDim.x * 256)
        h0_body(i >> 7, (i & 127) * 8, list, xi, ys, hbf, bi, bhn, b0, bw_log);
}

// ---------- big buckets: BM=256, BK=32 (halves Wht restaging per output) ----------
// LDS/buf: A 256x32 u16 (16KB) + B 192x32 (12KB) = 28KB; x2 = 56KB -> 2 blocks/CU.
#define S2STR 32
#define S2AB 0
#define S2BB 8192
#define S2LB 14336
__global__ __launch_bounds__(256, 2)
void k_scanh(int iter, const u16* __restrict__ list, const int* __restrict__ offs,
             const int* __restrict__ counts, const u16* __restrict__ posof,
             u16* hbf, const u16* __restrict__ xi,
             float* ys, const u16* __restrict__ Wht,
             const float* __restrict__ bi, const float* __restrict__ bhn,
             int b0, int bw_log)
{
    const int count = counts[iter];
    if (count <= 0) return;
    const int off = offs[iter];
    const int nMt = (count + 255) >> 8;
    const int nTiles = nMt * 16;
    const int bwm = (1 << bw_log) - 1;
    const int bwv = 1 << bw_log;

    __shared__ __align__(16) u16 lds[2][S2LB];

    const int tid = threadIdx.x;
    const int lane = tid & 63;
    const int w = tid >> 6;
    const int wr = w >> 1;           // 0..1 -> 128 rows each
    const int wc = w & 1;            // 0..1 -> 32 cols each
    const int l15 = lane & 15;
    const int l4 = lane >> 4;
    const int lrow = lane >> 2;      // 0..15
    const int slot = lane & 3;       // 16B slot in 64B row

    for (int tile = blockIdx.x; tile < nTiles; tile += gridDim.x){
        const int mtg = tile >> 4;
        const int cg = tile & 15;
        const int m0 = mtg * 256;
        const int c0 = cg * 64;

        const u16* pa[4];
        #pragma unroll
        for (int c = 0; c < 4; ++c){
            const int r = c * 64 + w * 16 + lrow;
            const int cid = list[off + min(m0 + r, count - 1)];
            pa[c] = hbf + (size_t)posof[cid - bwv] * 1024 + slot * 8;
        }
        const u16* pw[3];
        #pragma unroll
        for (int c = 0; c < 3; ++c)
            pw[c] = Wht + (size_t)(c * 1024 + c0 + w * 16 + lrow) * 1024 + slot * 8;

        f32x4 acc[3][8][2];
        #pragma unroll
        for (int gi = 0; gi < 3; ++gi)
            #pragma unroll
            for (int rf = 0; rf < 8; ++rf)
                #pragma unroll
                for (int cf = 0; cf < 2; ++cf)
                    acc[gi][rf][cf] = (f32x4){0.f, 0.f, 0.f, 0.f};

        { // prologue: stage k-tile 0
            u16* N = lds[0];
            #pragma unroll
            for (int c = 0; c < 4; ++c)
                glds16(pa[c], &N[S2AB + (c * 64 + w * 16) * S2STR]);
            #pragma unroll
            for (int c = 0; c < 3; ++c)
                glds16(pw[c], &N[S2BB + (c * 64 + w * 16) * S2STR]);
        }
        __syncthreads();

        for (int kt = 0; kt < 32; ++kt){
            if (kt < 31){
                u16* N = lds[(kt + 1) & 1];
                const int ko = (kt + 1) * 32;
                #pragma unroll
                for (int c = 0; c < 4; ++c)
                    glds16(pa[c] + ko, &N[S2AB + (c * 64 + w * 16) * S2STR]);
                #pragma unroll
                for (int c = 0; c < 3; ++c)
                    glds16(pw[c] + ko, &N[S2BB + (c * 64 + w * 16) * S2STR]);
            }
            const u16* L = lds[kt & 1];
            bf16x8 ah[8];
            #pragma unroll
            for (int rf = 0; rf < 8; ++rf)
                ah[rf] = *(const bf16x8*)&L[S2AB + (wr * 128 + rf * 16 + l15) * S2STR + l4 * 8];
            #pragma unroll
            for (int g = 0; g < 3; ++g){
                #pragma unroll
                for (int cf = 0; cf < 2; ++cf){
                    bf16x8 bh = *(const bf16x8*)&L[S2BB + (g * 64 + wc * 32 + cf * 16 + l15) * S2STR + l4 * 8];
                    #pragma unroll
                    for (int rf = 0; rf < 8; ++rf)
                        acc[g][rf][cf] = __builtin_amdgcn_mfma_f32_16x16x32_bf16(
                            ah[rf], bh, acc[g][rf][cf], 0, 0, 0);
                }
            }
            __syncthreads();
        }

        // epilogue: gates; nt xi loads, write fp32 ys + bf16 hbf
        #pragma unroll
        for (int cf = 0; cf < 2; ++cf){
            const int colh = c0 + wc * 32 + cf * 16 + l15;
            const float b_r = bi[colh];
            const float b_z = bi[1024 + colh];
            const float b_n = bi[2048 + colh];
            const float b_h = bhn[colh];
            #pragma unroll
            for (int rf = 0; rf < 8; ++rf){
                #pragma unroll
                for (int m = 0; m < 4; ++m){
                    const int rloc = wr * 128 + rf * 16 + l4 * 4 + m;
                    const int P = off + min(m0 + rloc, count - 1);
                    const int cid = list[P];
                    const int p = ((cid >> bw_log) << 7) + b0 + (cid & bwm);
                    const u16* xr = xi + (size_t)cid * 3072 + colh;
                    const float xrv = bf2f(__builtin_nontemporal_load(xr));
                    const float xzv = bf2f(__builtin_nontemporal_load(xr + 1024));
                    const float xnv = bf2f(__builtin_nontemporal_load(xr + 2048));
                    const float rr = 1.f / (1.f + __expf(-(xrv + b_r + acc[0][rf][cf][m])));
                    const float zz = 1.f / (1.f + __expf(-(xzv + b_z + acc[1][rf][cf][m])));
                    const float nn = tanhf(xnv + b_n + rr * (acc[2][rf][cf][m] + b_h));
                    const float hp = ys[(size_t)(p - 128) * 1024 + colh];
                    const float hv = (1.f - zz) * nn + zz * hp;
                    ys[(size_t)p * 1024 + colh] = hv;
                    hbf[(size_t)P * 1024 + colh] = f2bf(hv);
                }
            }
        }
    }
}

// ---------- tail GEMM tile body (BM=128, BK=64, 80KB) ----------
#define SSTR64 64
#define SAB 0
#define SBB 8192
#define SLB64 20480

__device__ __forceinline__ void scanh_tile(int mtg, int cg, int count, int off,
    int b0, int bw_log, const u16* __restrict__ list, const u16* __restrict__ posof,
    u16* hbf, const u16* __restrict__ xi, float* ys, const u16* __restrict__ Wht,
    const float* __restrict__ bi, const float* __restrict__ bhn,
    u16 (*lds)[SLB64])
{
    const int bwm = (1 << bw_log) - 1;
    const int bwv = 1 << bw_log;
    const int tid = threadIdx.x;
    const int lane = tid & 63;
    const int w = tid >> 6;
    const int wr = w >> 1;
    const int wc = w & 1;
    const int l15 = lane & 15;
    const int l4 = lane >> 4;
    const int lrow = lane >> 3;
    const int slot = lane & 7;

    const int m0 = mtg * 128;
    const int c0 = cg * 64;

    const u16* pa[4];
    #pragma unroll
    for (int c = 0; c < 4; ++c){
        const int r = c * 32 + w * 8 + lrow;
        const int cid = list[off + min(m0 + r, count - 1)];
        pa[c] = hbf + (size_t)posof[cid - bwv] * 1024 + slot * 8;
    }
    const u16* pw[6];
    #pragma unroll
    for (int c = 0; c < 6; ++c){
        const int br = c * 32 + w * 8 + lrow;
        const int g = br >> 6, ri = br & 63;
        pw[c] = Wht + (size_t)(g * 1024 + c0 + ri) * 1024 + slot * 8;
    }

    f32x4 acc[3][4][2];
    #pragma unroll
    for (int gi = 0; gi < 3; ++gi)
        #pragma unroll
        for (int rf = 0; rf < 4; ++rf)
            #pragma unroll
            for (int cf = 0; cf < 2; ++cf)
                acc[gi][rf][cf] = (f32x4){0.f, 0.f, 0.f, 0.f};

    {
        u16* N = lds[0];
        #pragma unroll
        for (int c = 0; c < 4; ++c)
            glds16(pa[c], &N[SAB + (c * 32 + w * 8) * SSTR64]);
        #pragma unroll
        for (int c = 0; c < 6; ++c)
            glds16(pw[c], &N[SBB + (c * 32 + w * 8) * SSTR64]);
    }
    __syncthreads();

    for (int kt = 0; kt < 16; ++kt){
        if (kt < 15){
            u16* N = lds[(kt + 1) & 1];
            const int ko = (kt + 1) * 64;
            #pragma unroll
            for (int c = 0; c < 4; ++c)
                glds16(pa[c] + ko, &N[SAB + (c * 32 + w * 8) * SSTR64]);
            #pragma unroll
            for (int c = 0; c < 6; ++c)
                glds16(pw[c] + ko, &N[SBB + (c * 32 + w * 8) * SSTR64]);
        }
        const u16* L = lds[kt & 1];
        #pragma unroll
        for (int kk = 0; kk < 2; ++kk){
            bf16x8 ah[4];
            #pragma unroll
            for (int rf = 0; rf < 4; ++rf)
                ah[rf] = *(const bf16x8*)&L[SAB + (wr * 64 + rf * 16 + l15) * SSTR64 + kk * 32 + l4 * 8];
            #pragma unroll
            for (int g = 0; g < 3; ++g){
                #pragma unroll
                for (int cf = 0; cf < 2; ++cf){
                    bf16x8 bh = *(const bf16x8*)&L[SBB + (g * 64 + wc * 32 + cf * 16 + l15) * SSTR64 + kk * 32 + l4 * 8];
                    #pragma unroll
                    for (int rf = 0; rf < 4; ++rf)
                        acc[g][rf][cf] = __builtin_amdgcn_mfma_f32_16x16x32_bf16(
                            ah[rf], bh, acc[g][rf][cf], 0, 0, 0);
                }
            }
        }
        __syncthreads();
    }

    #pragma unroll
    for (int cf = 0; cf < 2; ++cf){
        const int colh = c0 + wc * 32 + cf * 16 + l15;
        const float b_r = bi[colh];
        const float b_z = bi[1024 + colh];
        const float b_n = bi[2048 + colh];
        const float b_h = bhn[colh];
        #pragma unroll
        for (int rf = 0; rf < 4; ++rf){
            #pragma unroll
            for (int m = 0; m < 4; ++m){
                const int rloc = wr * 64 + rf * 16 + l4 * 4 + m;
                const int P = off + min(m0 + rloc, count - 1);
                const int cid = list[P];
                const int p = ((cid >> bw_log) << 7) + b0 + (cid & bwm);
                const u16* xr = xi + (size_t)cid * 3072 + colh;
                const float xrv = bf2f(__builtin_nontemporal_load(xr));
                const float xzv = bf2f(__builtin_nontemporal_load(xr + 1024));
                const float xnv = bf2f(__builtin_nontemporal_load(xr + 2048));
                const float rr = 1.f / (1.f + __expf(-(xrv + b_r + acc[0][rf][cf][m])));
                const float zz = 1.f / (1.f + __expf(-(xzv + b_z + acc[1][rf][cf][m])));
                const float nn = tanhf(xnv + b_n + rr * (acc[2][rf][cf][m] + b_h));
                const float hp = ys[(size_t)(p - 128) * 1024 + colh];
                const float hv = (1.f - zz) * nn + zz * hp;
                ys[(size_t)p * 1024 + colh] = hv;
                hbf[(size_t)P * 1024 + colh] = f2bf(hv);
            }
        }
    }
}

// ---------- tail buckets (a >= aStart): single dispatch with flag sync ----------
__global__ __launch_bounds__(256, 2)
void k_scan_all(const u16* __restrict__ list, const int* __restrict__ offs,
                const int* __restrict__ counts, const u16* __restrict__ posof,
                u16* hbf, const u16* __restrict__ xi, float* ys,
                const u16* __restrict__ Wht, const float* __restrict__ bi,
                const float* __restrict__ bhn, int b0, int bw_log,
                const int* __restrict__ gbase, const int* __restrict__ tbase,
                u32* __restrict__ fin, int aStart)
{
    __shared__ __align__(16) u16 lds[2][SLB64];
    const int T = tbase[NITER];
    const int tid = threadIdx.x;

    for (int idx = tbase[aStart] + blockIdx.x; idx < T; idx += gridDim.x){
        int a = aStart;
        while (tbase[a + 1] <= idx) ++a;

        const int rel = idx - tbase[a];
        const int mtg = rel >> 4, cg = rel & 15;
        const int count = counts[a], off = offs[a];
        if (count <= 0) continue;

        if (a > aStart){
            if (tid == 0){
                const int bwv = 1 << bw_log;
                const int cidF = list[off + min(mtg * 128, count - 1)];
                const int cidL = list[off + min(mtg * 128 + 127, count - 1)];
                const int opv = offs[a - 1];
                const int glo = gbase[a - 1] + ((posof[cidF - bwv] - opv) >> 7);
                const int ghi = gbase[a - 1] + ((posof[cidL - bwv] - opv) >> 7);
                for (int g = glo; g <= ghi; ++g){
                    while (__hip_atomic_load(&fin[g], __ATOMIC_RELAXED, __HIP_MEMORY_SCOPE_AGENT) < 16u)
                        __builtin_amdgcn_s_sleep(8);
                }
                (void)__hip_atomic_load(&fin[ghi], __ATOMIC_ACQUIRE, __HIP_MEMORY_SCOPE_AGENT);
            }
            __syncthreads();
        }

        scanh_tile(mtg, cg, count, off, b0, bw_log, list, posof, hbf, xi, ys,
                   Wht, bi, bhn, lds);

        __syncthreads();
        if (tid == 0)
            __hip_atomic_fetch_add(&fin[gbase[a] + mtg], 1u,
                                   __ATOMIC_RELEASE, __HIP_MEMORY_SCOPE_AGENT);
    }
}

// ---------- small-ws fallback: fused x+h kernel ----------
__global__ __launch_bounds__(256, 2)
void k_scan_fb(int iter, const u16* __restrict__ list, const int* __restrict__ offs,
               const int* __restrict__ counts, const float* __restrict__ ins,
               float* ys, const u16* __restrict__ Wit, const u16* __restrict__ Wht,
               const float* __restrict__ bi, const float* __restrict__ bhn)
{
    const int count = counts[iter];
    if (count <= 0) return;
    const int off = offs[iter];
    const int nTiles = ((count + 127) >> 7) * 16;
    const bool hasH = (iter > 0);

    __shared__ __align__(16) u16 lds[2][20480];

    const int tid = threadIdx.x;
    const int lane = tid & 63;
    const int w = tid >> 6;
    const int wr = w >> 1;
    const int wc = w & 1;
    const int l15 = lane & 15;
    const int l4 = lane >> 4;
    const int swz = ((l4 ^ (lane & 3)) * 8);
    const int sr = tid >> 2;
    const int sq = tid & 3;
    const int swzW = ((sq ^ (sr & 3)) * 8);

    for (int tile = blockIdx.x; tile < nTiles; tile += gridDim.x){
        const int mt = tile >> 4;
        const int cg = tile & 15;
        const int m0 = mt * 128;
        const int c0 = cg * 64;

        const int px0i = list[off + min(m0 + sr, count - 1)];
        const int px1i = list[off + min(m0 + 64 + sr, count - 1)];
        const float* px0 = ins + (size_t)px0i * 1024 + sq * 8;
        const float* px1 = ins + (size_t)px1i * 1024 + sq * 8;
        const float* ph0 = ys + (ptrdiff_t)(px0i - 128) * 1024 + sq * 8;
        const float* ph1 = ys + (ptrdiff_t)(px1i - 128) * 1024 + sq * 8;
        const u16* pb[6];
        #pragma unroll
        for (int pp = 0; pp < 6; ++pp){
            const int g = pp >> 1, m = pp & 1;
            const u16* W = m ? Wht : Wit;
            pb[pp] = W + (size_t)(g * 1024 + c0 + sr) * 1024 + sq * 8;
        }

        f32x4 acc[4][4][2];
        #pragma unroll
        for (int gi = 0; gi < 4; ++gi)
            #pragma unroll
            for (int rf = 0; rf < 4; ++rf)
                #pragma unroll
                for (int cf = 0; cf < 2; ++cf)
                    acc[gi][rf][cf] = (f32x4){0.f, 0.f, 0.f, 0.f};

        {
            u16* N = lds[0];
            *(u32x4*)&N[sr * 32 + swzW] = pack8(*(const f32x4*)(px0), *(const f32x4*)(px0 + 4));
            *(u32x4*)&N[(64 + sr) * 32 + swzW] = pack8(*(const f32x4*)(px1), *(const f32x4*)(px1 + 4));
            if (hasH){
                *(u32x4*)&N[(128 + sr) * 32 + swzW] = pack8(*(const f32x4*)(ph0), *(const f32x4*)(ph0 + 4));
                *(u32x4*)&N[(192 + sr) * 32 + swzW] = pack8(*(const f32x4*)(ph1), *(const f32x4*)(ph1 + 4));
            }
            #pragma unroll
            for (int pp = 0; pp < 6; ++pp)
                *(u32x4*)&N[8192 + (pp * 64 + sr) * 32 + swzW] = *(const u32x4*)(pb[pp]);
        }
        __syncthreads();

        int cur = 0;
        #pragma unroll 2
        for (int kt = 0; kt < 32; ++kt){
            f32x4 nx0a, nx0b, nx1a, nx1b, nh0a, nh0b, nh1a, nh1b;
            u32x4 sb[6];
            const bool more = (kt < 31);
            if (more){
                const int kof = (kt + 1) * 32;
                nx0a = *(const f32x4*)(px0 + kof); nx0b = *(const f32x4*)(px0 + kof + 4);
                nx1a = *(const f32x4*)(px1 + kof); nx1b = *(const f32x4*)(px1 + kof + 4);
                if (hasH){
                    nh0a = *(const f32x4*)(ph0 + kof); nh0b = *(const f32x4*)(ph0 + kof + 4);
                    nh1a = *(const f32x4*)(ph1 + kof); nh1b = *(const f32x4*)(ph1 + kof + 4);
                }
                #pragma unroll
                for (int pp = 0; pp < 6; ++pp) sb[pp] = *(const u32x4*)(pb[pp] + kof);
            }

            const u16* L = lds[cur];
            bf16x8 ax[4], ah[4];
            #pragma unroll
            for (int rf = 0; rf < 4; ++rf)
                ax[rf] = *(const bf16x8*)&L[(wr * 64 + rf * 16 + l15) * 32 + swz];
            if (hasH){
                #pragma unroll
                for (int rf = 0; rf < 4; ++rf)
                    ah[rf] = *(const bf16x8*)&L[(128 + wr * 64 + rf * 16 + l15) * 32 + swz];
            }
            #pragma unroll
            for (int g = 0; g < 3; ++g){
                #pragma unroll
                for (int cf = 0; cf < 2; ++cf){
                    const int brow = g * 128 + wc * 32 + cf * 16 + l15;
                    bf16x8 bv = *(const bf16x8*)&L[8192 + brow * 32 + swz];
                    const int gx = (g == 2) ? 2 : g;
                    #pragma unroll
                    for (int rf = 0; rf < 4; ++rf)
                        acc[gx][rf][cf] = __builtin_amdgcn_mfma_f32_16x16x32_bf16(
                            ax[rf], bv, acc[gx][rf][cf], 0, 0, 0);
                    if (hasH){
                        bf16x8 bh = *(const bf16x8*)&L[8192 + (brow + 64) * 32 + swz];
                        const int gh = (g == 2) ? 3 : g;
                        #pragma unroll
                        for (int rf = 0; rf < 4; ++rf)
                            acc[gh][rf][cf] = __builtin_amdgcn_mfma_f32_16x16x32_bf16(
                                ah[rf], bh, acc[gh][rf][cf], 0, 0, 0);
                    }
                }
            }

            if (more){
                u16* N = lds[cur ^ 1];
                *(u32x4*)&N[sr * 32 + swzW] = pack8(nx0a, nx0b);
                *(u32x4*)&N[(64 + sr) * 32 + swzW] = pack8(nx1a, nx1b);
                if (hasH){
                    *(u32x4*)&N[(128 + sr) * 32 + swzW] = pack8(nh0a, nh0b);
                    *(u32x4*)&N[(192 + sr) * 32 + swzW] = pack8(nh1a, nh1b);
                }
                #pragma unroll
                for (int pp = 0; pp < 6; ++pp)
                    *(u32x4*)&N[8192 + (pp * 64 + sr) * 32 + swzW] = sb[pp];
            }
            __syncthreads();
            cur ^= 1;
        }

        #pragma unroll
        for (int cf = 0; cf < 2; ++cf){
            const int colh = c0 + wc * 32 + cf * 16 + l15;
            const float b_r = bi[colh];
            const float b_z = bi[1024 + colh];
            const float b_n = bi[2048 + colh];
            const float b_h = bhn[colh];
            #pragma unroll
            for (int rf = 0; rf < 4; ++rf){
                #pragma unroll
                for (int m = 0; m < 4; ++m){
                    const int rloc = wr * 64 + rf * 16 + l4 * 4 + m;
                    const int p = list[off + min(m0 + rloc, count - 1)];
                    const float rr = 1.f / (1.f + __expf(-(acc[0][rf][cf][m] + b_r)));
                    const float zz = 1.f / (1.f + __expf(-(acc[1][rf][cf][m] + b_z)));
                    const float nn = tanhf(acc[2][rf][cf][m] + b_n + rr * (acc[3][rf][cf][m] + b_h));
                    float hp = 0.f;
                    if (hasH) hp = ys[(size_t)(p - 128) * 1024 + colh];
                    ys[(size_t)p * 1024 + colh] = (1.f - zz) * nn + zz * hp;
                }
            }
        }
    }
}

extern "C" void kernel_launch(void* const* d_in, const int* in_sizes, int n_in,
                              void* d_out, int out_size, void* d_ws, size_t ws_size,
                              hipStream_t stream)
{
    (void)in_sizes; (void)n_in; (void)out_size;
    const float* ins  = (const float*)d_in[0];
    const void*  rst  = d_in[1];
    const float* Wi   = (const float*)d_in[2];
    const float* bi   = (const float*)d_in[3];
    const float* Wh   = (const float*)d_in[4];
    const float* bhn  = (const float*)d_in[5];
    float* ys = (float*)d_out;
    u8* ws = (u8*)d_ws;

    const size_t A = 12648448;
    u16* Wit    = (u16*)(ws + 0);
    u16* Wht    = (u16*)(ws + 6291456);
    u8*  age    = ws + 12582912;           // 64 KB
    int* counts = (int*)(ws + A + 0);
    int* offs   = (int*)(ws + A + 256);
    int* gbase  = (int*)(ws + A + 512);
    int* tbase  = (int*)(ws + A + 768);
    u32* fin    = (u32*)(ws + A + 1024);   // 4 KB
    int* flag   = (int*)(ws + A + 5120);   // outside memset range
    int* bh     = (int*)(ws + A + 5376);
    int* bb     = (int*)(ws + A + 54528);
    u16* posof  = (u16*)(ws + A + 103680);
    u16* list   = (u16*)(ws + A + 234752);
    u16* insbf  = (u16*)(ws + 13014272);   // Mrows*2KB (aliased as hbf after k_xi)

    int bw = 0, bwlog = 0;
    {
        const size_t base = 13014272;
        if (ws_size >= base + (size_t)TT * 128 * 8192)      { bw = 128; bwlog = 7; }
        else if (ws_size >= base + (size_t)TT * 64 * 8192)  { bw = 64;  bwlog = 6; }
        else if (ws_size >= base + (size_t)TT * 32 * 8192)  { bw = 32;  bwlog = 5; }
    }

    k_detect<<<1, 256, 0, stream>>>((const u8*)rst, flag);
    k_packT<<<dim3(32, 96, 2), dim3(32, 8), 0, stream>>>(Wi, Wh, Wit, Wht);

    if (bw == 0){
        const int Mr = TT * BB, NB = Mr / 256;
        hipMemsetAsync(ws + A, 0, 5120, stream);
        k_ages<<<NB, 256, 0, stream>>>(rst, flag, 0, 7, age, bh);
        k_offsets<<<1, 64, 0, stream>>>(bh, NB, counts, offs, gbase, tbase, bb);
        k_scatter<<<NB, 256, 0, stream>>>(age, offs, bb, list, posof);
        for (int it = 0; it < NITER; ++it)
            k_scan_fb<<<512, 256, 0, stream>>>(it, list, offs, counts, ins, ys, Wit, Wht, bi, bhn);
        return;
    }

    u16* xi = insbf + (size_t)TT * bw * 1024;
    u16* hbf = insbf;                      // alias: insbf fully consumed by k_xi first
    const int nch = BB / bw;
    const int Mrows = TT * bw;
    const int NB = Mrows / 256;

    for (int c = 0; c < nch; ++c){
        const int b0 = c * bw;
        hipMemsetAsync(ws + A, 0, 5120, stream);   // counts/offs/gbase/tbase/fin
        k_ages<<<NB, 256, 0, stream>>>(rst, flag, b0, bwlog, age, bh);
        k_offsets<<<1, 64, 0, stream>>>(bh, NB, counts, offs, gbase, tbase, bb);
        k_scatter<<<NB, 256, 0, stream>>>(age, offs, bb, list, posof);
        k_tobf<<<2048, 256, 0, stream>>>(ins, insbf, b0, bwlog, Mrows * 128);
        k_xi<<<3072, 256, 0, stream>>>(insbf, Wit, xi, Mrows);
        k_h0<<<2048, 256, 0, stream>>>(list, counts, xi, ys, hbf, bi, bhn, b0, bwlog);
        for (int it = 1; it < ASTART; ++it){
            int est = ((Mrows >> (it + 1)) / 256 + 1) * 16;
            int grid = est < 32 ? 32 : (est > 512 ? 512 : est);
            k_scanh<<<grid, 256, 0, stream>>>(it, list, offs, counts, posof, hbf, xi,
                                              ys, Wht, bi, bhn, b0, bwlog);
        }
        k_scan_all<<<512, 256, 0, stream>>>(list, offs, counts, posof, hbf, xi, ys,
                                            Wht, bi, bhn, b0, bwlog, gbase, tbase,
                                            fin, ASTART);
    }
}

// Round 15
// 1726.113 us; speedup vs baseline: 1.3075x; 1.3075x over previous
//
#include <hip/hip_runtime.h>
#include <stdint.h>

typedef unsigned short u16;
typedef unsigned int u32;
typedef unsigned char u8;

typedef __attribute__((ext_vector_type(4))) float f32x4;
typedef __attribute__((ext_vector_type(4))) u32 u32x4;
typedef __attribute__((ext_vector_type(8))) __bf16 bf16x8;

#define NITER 48
#define TT 512
#define BB 128
#define ASTART 6   // buckets >= ASTART run in the single flag-sync dispatch

__device__ __forceinline__ u16 f2bf(float f){
    u32 u = __builtin_bit_cast(u32, f);
    u = (u + 0x7FFFu + ((u >> 16) & 1u)) >> 16;
    return (u16)u;
}
__device__ __forceinline__ float bf2f(u16 v){
    u32 u = ((u32)v) << 16;
    return __builtin_bit_cast(float, u);
}
__device__ __forceinline__ u32x4 pack8(f32x4 a, f32x4 b){
    u32x4 u;
    u[0] = (u32)f2bf(a[0]) | ((u32)f2bf(a[1]) << 16);
    u[1] = (u32)f2bf(a[2]) | ((u32)f2bf(a[3]) << 16);
    u[2] = (u32)f2bf(b[0]) | ((u32)f2bf(b[1]) << 16);
    u[3] = (u32)f2bf(b[2]) | ((u32)f2bf(b[3]) << 16);
    return u;
}
__device__ __forceinline__ void glds16(const u16* g, u16* l){
    __builtin_amdgcn_global_load_lds(
        (const __attribute__((address_space(1))) u32*)g,
        (__attribute__((address_space(3))) u32*)l, 16, 0, 0);
}

// ---------- resets dtype detection ----------
__global__ void k_detect(const u8* __restrict__ r, int* __restrict__ flag){
    __shared__ int nz[4];
    if (threadIdx.x < 4) nz[threadIdx.x] = 0;
    __syncthreads();
    int loc[4] = {0,0,0,0};
    const int base = threadIdx.x * 16;
    #pragma unroll
    for (int i = 0; i < 16; ++i) if (r[base + i]) loc[i & 3] = 1;
    #pragma unroll
    for (int j = 0; j < 4; ++j) if (loc[j]) atomicOr(&nz[j], 1);
    __syncthreads();
    if (threadIdx.x == 0){
        int f;
        if (nz[0] && !nz[1] && !nz[2] && !nz[3]) f = 0;
        else if (!nz[0] && !nz[1] && (nz[2] || nz[3])) f = 2;
        else f = 1;
        *flag = f;
    }
}

__device__ __forceinline__ int reset_at(const void* r, int f, int idx){
    if (f == 0) return ((const int*)r)[idx] != 0;
    if (f == 1) return ((const u8*)r)[idx] != 0;
    return ((const float*)r)[idx] != 0.f;
}

// ---------- ages + per-block histogram (deterministic) ----------
__global__ void k_ages(const void* __restrict__ resets, const int* __restrict__ flag,
                       int b0, int bw_log, u8* __restrict__ age, int* __restrict__ bh){
    __shared__ int lc[NITER];
    const int tid = threadIdx.x;
    if (tid < NITER) lc[tid] = 0;
    __syncthreads();
    const int cid = blockIdx.x * 256 + tid;
    const int f = *flag;
    const int bwm = (1 << bw_log) - 1;
    const int t = cid >> bw_log, b = b0 + (cid & bwm);
    int a = 0, tt = t;
    while (tt > 0 && !reset_at(resets, f, tt * BB + b)){ ++a; --tt; }
    if (a > NITER - 1) a = NITER - 1;
    age[cid] = (u8)a;
    atomicAdd(&lc[a], 1);
    __syncthreads();
    if (tid < NITER) bh[blockIdx.x * NITER + tid] = lc[tid];
}

// ---------- offsets + per-block bases + group/tile bases ----------
__global__ void k_offsets(const int* __restrict__ bh, int NB,
                          int* __restrict__ counts, int* __restrict__ offs,
                          int* __restrict__ gbase, int* __restrict__ tbase,
                          int* __restrict__ bb){
    const int a = threadIdx.x;
    if (a < NITER){
        int run = 0;
        for (int b = 0; b < NB; ++b){
            bb[b * NITER + a] = run;
            run += bh[b * NITER + a];
        }
        counts[a] = run;
    }
    __syncthreads();
    if (a == 0){
        int o = 0;
        for (int i = 0; i < NITER; ++i){ offs[i] = o; o += counts[i]; }
        offs[NITER] = o;
        int g = 0, t = 0;
        for (int i = 0; i < NITER; ++i){
            const int ng = (counts[i] + 127) >> 7;
            gbase[i] = g; g += ng;
            tbase[i] = t; t += (i == 0) ? ng : ng * 16;
        }
        gbase[NITER] = g;
        tbase[NITER] = t;
    }
}

// ---------- stable scatter: bucket-internal order == cid order (chain order) ----------
__global__ void k_scatter(const u8* __restrict__ age, const int* __restrict__ offs,
                          const int* __restrict__ bb,
                          u16* __restrict__ list, u16* __restrict__ posof){
    __shared__ u8 sa[256];
    const int tid = threadIdx.x;
    const int cid = blockIdx.x * 256 + tid;
    const int a = age[cid];
    sa[tid] = (u8)a;
    __syncthreads();
    int rank = 0;
    for (int j = 0; j < tid; ++j) rank += (sa[j] == (u8)a);
    const int pos = offs[a] + bb[blockIdx.x * NITER + a] + rank;
    list[pos] = (u16)cid;
    posof[cid] = (u16)pos;
}

// ---------- weight pack: Wt[n][k] = bf16(W[k][n]) ----------
__global__ void k_packT(const float* __restrict__ Wi, const float* __restrict__ Wh,
                        u16* __restrict__ Wit, u16* __restrict__ Wht){
    __shared__ float tl[32][33];
    const int kb = blockIdx.x * 32;
    const int nb = blockIdx.y * 32;
    const float* W = blockIdx.z ? Wh : Wi;
    u16* Wt = blockIdx.z ? Wht : Wit;
    const int tx = threadIdx.x;
    for (int r = threadIdx.y; r < 32; r += 8)
        tl[r][tx] = W[(size_t)(kb + r) * 3072 + nb + tx];
    __syncthreads();
    for (int r = threadIdx.y; r < 32; r += 8)
        Wt[(size_t)(nb + r) * 1024 + kb + tx] = f2bf(tl[tx][r]);
}

// ---------- fp32 -> bf16 input conversion (nt loads: ins is read exactly once) ----------
__global__ void k_tobf(const float* __restrict__ ins, u16* __restrict__ insbf,
                       int b0, int bw_log, int total8){
    const int bwm = (1 << bw_log) - 1;
    for (int i = blockIdx.x * 256 + threadIdx.x; i < total8; i += gridDim.x * 256){
        const int cid = i >> 7;
        const int c8 = (i & 127) * 8;
        const int t = cid >> bw_log, j = cid & bwm;
        const float* src = ins + (size_t)(t * BB + b0 + j) * 1024 + c8;
        f32x4 a = __builtin_nontemporal_load((const f32x4*)src);
        f32x4 b = __builtin_nontemporal_load((const f32x4*)(src + 4));
        *(u32x4*)(insbf + (size_t)cid * 1024 + c8) = pack8(a, b);
    }
}

// ---------- xi = insbf @ Wit^T : m97-style, LDS epilogue, nt xi stores ----------
__global__ __launch_bounds__(256, 4)
void k_xi(const u16* __restrict__ insbf, const u16* __restrict__ Wit,
          u16* __restrict__ xi, int Mrows)
{
    __shared__ __align__(16) u16 lds[2][8192];
    const int tid = threadIdx.x;
    const int lane = tid & 63;
    const int w = tid >> 6;
    const int wr = w >> 1, wc = w & 1;
    const int l15 = lane & 15;
    const int l4 = lane >> 4;

    const int nMt = Mrows >> 7;
    const int nTiles = nMt * 24;

    for (int idx = blockIdx.x; idx < nTiles; idx += gridDim.x){
        const int mt = idx / 24;
        const int cg = idx - mt * 24;
        const int m0 = mt * 128;
        const int c0 = cg * 128;

        const u16* ga0 = insbf + (size_t)(m0 + w * 16 + (lane >> 2)) * 1024 + (lane & 3) * 8;
        const u16* ga1 = ga0 + (size_t)64 * 1024;
        const u16* gb0 = Wit + (size_t)(c0 + w * 16 + (lane >> 2)) * 1024 + (lane & 3) * 8;
        const u16* gb1 = gb0 + (size_t)64 * 1024;

        f32x4 acc[4][4];
        #pragma unroll
        for (int i = 0; i < 4; ++i)
            #pragma unroll
            for (int j = 0; j < 4; ++j)
                acc[i][j] = (f32x4){0.f, 0.f, 0.f, 0.f};

        {
            u16* Lb = lds[0];
            glds16(ga0, &Lb[w * 512]);
            glds16(ga1, &Lb[2048 + w * 512]);
            glds16(gb0, &Lb[4096 + w * 512]);
            glds16(gb1, &Lb[6144 + w * 512]);
        }
        __syncthreads();

        for (int kt = 0; kt < 32; ++kt){
            if (kt < 31){
                u16* Nb = lds[(kt + 1) & 1];
                const int ko = (kt + 1) * 32;
                glds16(ga0 + ko, &Nb[w * 512]);
                glds16(ga1 + ko, &Nb[2048 + w * 512]);
                glds16(gb0 + ko, &Nb[4096 + w * 512]);
                glds16(gb1 + ko, &Nb[6144 + w * 512]);
            }
            const u16* L = lds[kt & 1];
            bf16x8 ax[4], bx[4];
            #pragma unroll
            for (int rf = 0; rf < 4; ++rf)
                ax[rf] = *(const bf16x8*)&L[(wr * 64 + rf * 16 + l15) * 32 + l4 * 8];
            #pragma unroll
            for (int cf = 0; cf < 4; ++cf)
                bx[cf] = *(const bf16x8*)&L[4096 + (wc * 64 + cf * 16 + l15) * 32 + l4 * 8];
            #pragma unroll
            for (int rf = 0; rf < 4; ++rf)
                #pragma unroll
                for (int cf = 0; cf < 4; ++cf)
                    acc[rf][cf] = __builtin_amdgcn_mfma_f32_16x16x32_bf16(
                        ax[rf], bx[cf], acc[rf][cf], 0, 0, 0);
            __syncthreads();
        }

        u16* region = ((u16*)lds) + w * 4096;
        #pragma unroll
        for (int rf = 0; rf < 4; ++rf)
            #pragma unroll
            for (int cf = 0; cf < 4; ++cf)
                #pragma unroll
                for (int m = 0; m < 4; ++m)
                    region[(rf * 16 + l4 * 4 + m) * 64 + cf * 16 + l15] = f2bf(acc[rf][cf][m]);
        #pragma unroll
        for (int rep = 0; rep < 8; ++rep){
            const int r = rep * 8 + (lane >> 3);
            const int cc = (lane & 7) * 8;
            u32x4 v = *(u32x4*)&region[r * 64 + cc];
            __builtin_nontemporal_store(v,
                (u32x4*)(xi + (size_t)(m0 + wr * 64 + r) * 3072 + c0 + wc * 64 + cc));
        }
        __syncthreads();
    }
}

// ---------- age-0 elementwise body (nt xi loads: read-once stream) ----------
__device__ __forceinline__ void h0_body(int row, int c8, const u16* __restrict__ list,
    const u16* __restrict__ xi, float* __restrict__ ys, u16* __restrict__ hbf,
    const float* __restrict__ bi, const float* __restrict__ bhn, int b0, int bw_log)
{
    const int bwm = (1 << bw_log) - 1;
    const int cid = list[row];
    const int p = ((cid >> bw_log) << 7) + b0 + (cid & bwm);
    const u16* xr = xi + (size_t)cid * 3072 + c8;
    u32x4 vr = __builtin_nontemporal_load((const u32x4*)xr);
    u32x4 vz = __builtin_nontemporal_load((const u32x4*)(xr + 1024));
    u32x4 vn = __builtin_nontemporal_load((const u32x4*)(xr + 2048));
    f32x4 br0 = *(const f32x4*)(bi + c8),        br1 = *(const f32x4*)(bi + c8 + 4);
    f32x4 bz0 = *(const f32x4*)(bi + 1024 + c8), bz1 = *(const f32x4*)(bi + 1024 + c8 + 4);
    f32x4 bn0 = *(const f32x4*)(bi + 2048 + c8), bn1 = *(const f32x4*)(bi + 2048 + c8 + 4);
    f32x4 bh0 = *(const f32x4*)(bhn + c8),       bh1 = *(const f32x4*)(bhn + c8 + 4);
    float out[8];
    #pragma unroll
    for (int e = 0; e < 8; ++e){
        const float xrv = bf2f((u16)(vr[e >> 1] >> ((e & 1) * 16)));
        const float xzv = bf2f((u16)(vz[e >> 1] >> ((e & 1) * 16)));
        const float xnv = bf2f((u16)(vn[e >> 1] >> ((e & 1) * 16)));
        const float brv = (e < 4) ? br0[e] : br1[e - 4];
        const float bzv = (e < 4) ? bz0[e] : bz1[e - 4];
        const float bnv = (e < 4) ? bn0[e] : bn1[e - 4];
        const float bhv = (e < 4) ? bh0[e] : bh1[e - 4];
        const float rr = 1.f / (1.f + __expf(-(xrv + brv)));
        const float zz = 1.f / (1.f + __expf(-(xzv + bzv)));
        const float nn = tanhf(xnv + bnv + rr * bhv);
        out[e] = (1.f - zz) * nn;
    }
    float* dst = ys + (size_t)p * 1024 + c8;
    f32x4 o0 = (f32x4){out[0], out[1], out[2], out[3]};
    f32x4 o1 = (f32x4){out[4], out[5], out[6], out[7]};
    *(f32x4*)dst = o0;
    *(f32x4*)(dst + 4) = o1;
    *(u32x4*)(hbf + (size_t)row * 1024 + c8) = pack8(o0, o1);
}

__global__ void k_h0(const u16* __restrict__ list, const int* __restrict__ counts,
                     const u16* __restrict__ xi, float* __restrict__ ys,
                     u16* __restrict__ hbf, const float* __restrict__ bi,
                     const float* __restrict__ bhn, int b0, int bw_log)
{
    const int total = counts[0] * 128;
    for (int i = blockIdx.x * 256 + threadIdx.x; i < total; i += gridDim.x * 256)
        h0_body(i >> 7, (i & 127) * 8, list, xi, ys, hbf, bi, bhn, b0, bw_log);
}

// ---------- GEMM tile body (BK=64) ----------
#define SSTR64 64
#define SAB 0
#define SBB 8192
#define SLB64 20480   // x2 buffers = 80 KB -> 2 blocks/CU

__device__ __forceinline__ void scanh_tile(int mtg, int cg, int count, int off,
    int b0, int bw_log, const u16* __restrict__ list, const u16* __restrict__ posof,
    u16* hbf, const u16* __restrict__ xi, float* ys, const u16* __restrict__ Wht,
    const float* __restrict__ bi, const float* __restrict__ bhn,
    u16 (*lds)[SLB64])
{
    const int bwm = (1 << bw_log) - 1;
    const int bwv = 1 << bw_log;
    const int tid = threadIdx.x;
    const int lane = tid & 63;
    const int w = tid >> 6;
    const int wr = w >> 1;
    const int wc = w & 1;
    const int l15 = lane & 15;
    const int l4 = lane >> 4;
    const int lrow = lane >> 3;
    const int slot = lane & 7;

    const int m0 = mtg * 128;
    const int c0 = cg * 64;

    const u16* pa[4];
    #pragma unroll
    for (int c = 0; c < 4; ++c){
        const int r = c * 32 + w * 8 + lrow;
        const int cid = list[off + min(m0 + r, count - 1)];
        pa[c] = hbf + (size_t)posof[cid - bwv] * 1024 + slot * 8;
    }
    const u16* pw[6];
    #pragma unroll
    for (int c = 0; c < 6; ++c){
        const int br = c * 32 + w * 8 + lrow;
        const int g = br >> 6, ri = br & 63;
        pw[c] = Wht + (size_t)(g * 1024 + c0 + ri) * 1024 + slot * 8;
    }

    f32x4 acc[3][4][2];
    #pragma unroll
    for (int gi = 0; gi < 3; ++gi)
        #pragma unroll
        for (int rf = 0; rf < 4; ++rf)
            #pragma unroll
            for (int cf = 0; cf < 2; ++cf)
                acc[gi][rf][cf] = (f32x4){0.f, 0.f, 0.f, 0.f};

    {
        u16* N = lds[0];
        #pragma unroll
        for (int c = 0; c < 4; ++c)
            glds16(pa[c], &N[SAB + (c * 32 + w * 8) * SSTR64]);
        #pragma unroll
        for (int c = 0; c < 6; ++c)
            glds16(pw[c], &N[SBB + (c * 32 + w * 8) * SSTR64]);
    }
    __syncthreads();

    for (int kt = 0; kt < 16; ++kt){
        if (kt < 15){
            u16* N = lds[(kt + 1) & 1];
            const int ko = (kt + 1) * 64;
            #pragma unroll
            for (int c = 0; c < 4; ++c)
                glds16(pa[c] + ko, &N[SAB + (c * 32 + w * 8) * SSTR64]);
            #pragma unroll
            for (int c = 0; c < 6; ++c)
                glds16(pw[c] + ko, &N[SBB + (c * 32 + w * 8) * SSTR64]);
        }
        const u16* L = lds[kt & 1];
        #pragma unroll
        for (int kk = 0; kk < 2; ++kk){
            bf16x8 ah[4];
            #pragma unroll
            for (int rf = 0; rf < 4; ++rf)
                ah[rf] = *(const bf16x8*)&L[SAB + (wr * 64 + rf * 16 + l15) * SSTR64 + kk * 32 + l4 * 8];
            #pragma unroll
            for (int g = 0; g < 3; ++g){
                #pragma unroll
                for (int cf = 0; cf < 2; ++cf){
                    bf16x8 bh = *(const bf16x8*)&L[SBB + (g * 64 + wc * 32 + cf * 16 + l15) * SSTR64 + kk * 32 + l4 * 8];
                    #pragma unroll
                    for (int rf = 0; rf < 4; ++rf)
                        acc[g][rf][cf] = __builtin_amdgcn_mfma_f32_16x16x32_bf16(
                            ah[rf], bh, acc[g][rf][cf], 0, 0, 0);
                }
            }
        }
        __syncthreads();
    }

    // epilogue: gates; nt xi loads (read-once), write fp32 ys + bf16 hbf
    #pragma unroll
    for (int cf = 0; cf < 2; ++cf){
        const int colh = c0 + wc * 32 + cf * 16 + l15;
        const float b_r = bi[colh];
        const float b_z = bi[1024 + colh];
        const float b_n = bi[2048 + colh];
        const float b_h = bhn[colh];
        #pragma unroll
        for (int rf = 0; rf < 4; ++rf){
            #pragma unroll
            for (int m = 0; m < 4; ++m){
                const int rloc = wr * 64 + rf * 16 + l4 * 4 + m;
                const int P = off + min(m0 + rloc, count - 1);
                const int cid = list[P];
                const int p = ((cid >> bw_log) << 7) + b0 + (cid & bwm);
                const u16* xr = xi + (size_t)cid * 3072 + colh;
                const float xrv = bf2f(__builtin_nontemporal_load(xr));
                const float xzv = bf2f(__builtin_nontemporal_load(xr + 1024));
                const float xnv = bf2f(__builtin_nontemporal_load(xr + 2048));
                const float rr = 1.f / (1.f + __expf(-(xrv + b_r + acc[0][rf][cf][m])));
                const float zz = 1.f / (1.f + __expf(-(xzv + b_z + acc[1][rf][cf][m])));
                const float nn = tanhf(xnv + b_n + rr * (acc[2][rf][cf][m] + b_h));
                const float hp = ys[(size_t)(p - 128) * 1024 + colh];
                const float hv = (1.f - zz) * nn + zz * hp;
                ys[(size_t)p * 1024 + colh] = hv;
                hbf[(size_t)P * 1024 + colh] = f2bf(hv);
            }
        }
    }
}

// ---------- big buckets: one dispatch per iteration ----------
__global__ __launch_bounds__(256, 2)
void k_scanh(int iter, const u16* __restrict__ list, const int* __restrict__ offs,
             const int* __restrict__ counts, const u16* __restrict__ posof,
             u16* hbf, const u16* __restrict__ xi,
             float* ys, const u16* __restrict__ Wht,
             const float* __restrict__ bi, const float* __restrict__ bhn,
             int b0, int bw_log)
{
    const int count = counts[iter];
    if (count <= 0) return;
    const int off = offs[iter];
    const int nTiles = ((count + 127) >> 7) * 16;
    __shared__ __align__(16) u16 lds[2][SLB64];
    for (int tile = blockIdx.x; tile < nTiles; tile += gridDim.x)
        scanh_tile(tile >> 4, tile & 15, count, off, b0, bw_log, list, posof,
                   hbf, xi, ys, Wht, bi, bhn, lds);
}

// ---------- tail buckets (a >= aStart): single dispatch with flag sync ----------
__global__ __launch_bounds__(256, 2)
void k_scan_all(const u16* __restrict__ list, const int* __restrict__ offs,
                const int* __restrict__ counts, const u16* __restrict__ posof,
                u16* hbf, const u16* __restrict__ xi, float* ys,
                const u16* __restrict__ Wht, const float* __restrict__ bi,
                const float* __restrict__ bhn, int b0, int bw_log,
                const int* __restrict__ gbase, const int* __restrict__ tbase,
                u32* __restrict__ fin, int aStart)
{
    __shared__ __align__(16) u16 lds[2][SLB64];
    const int T = tbase[NITER];
    const int tid = threadIdx.x;

    for (int idx = tbase[aStart] + blockIdx.x; idx < T; idx += gridDim.x){
        int a = aStart;
        while (tbase[a + 1] <= idx) ++a;

        const int rel = idx - tbase[a];
        const int mtg = rel >> 4, cg = rel & 15;
        const int count = counts[a], off = offs[a];
        if (count <= 0) continue;

        if (a > aStart){
            if (tid == 0){
                const int bwv = 1 << bw_log;
                const int cidF = list[off + min(mtg * 128, count - 1)];
                const int cidL = list[off + min(mtg * 128 + 127, count - 1)];
                const int opv = offs[a - 1];
                const int glo = gbase[a - 1] + ((posof[cidF - bwv] - opv) >> 7);
                const int ghi = gbase[a - 1] + ((posof[cidL - bwv] - opv) >> 7);
                for (int g = glo; g <= ghi; ++g){
                    while (__hip_atomic_load(&fin[g], __ATOMIC_RELAXED, __HIP_MEMORY_SCOPE_AGENT) < 16u)
                        __builtin_amdgcn_s_sleep(8);
                }
                (void)__hip_atomic_load(&fin[ghi], __ATOMIC_ACQUIRE, __HIP_MEMORY_SCOPE_AGENT);
            }
            __syncthreads();
        }

        scanh_tile(mtg, cg, count, off, b0, bw_log, list, posof, hbf, xi, ys,
                   Wht, bi, bhn, lds);

        __syncthreads();
        if (tid == 0)
            __hip_atomic_fetch_add(&fin[gbase[a] + mtg], 1u,
                                   __ATOMIC_RELEASE, __HIP_MEMORY_SCOPE_AGENT);
    }
}

// ---------- small-ws fallback: fused x+h kernel ----------
__global__ __launch_bounds__(256, 2)
void k_scan_fb(int iter, const u16* __restrict__ list, const int* __restrict__ offs,
               const int* __restrict__ counts, const float* __restrict__ ins,
               float* ys, const u16* __restrict__ Wit, const u16* __restrict__ Wht,
               const float* __restrict__ bi, const float* __restrict__ bhn)
{
    const int count = counts[iter];
    if (count <= 0) return;
    const int off = offs[iter];
    const int nTiles = ((count + 127) >> 7) * 16;
    const bool hasH = (iter > 0);

    __shared__ __align__(16) u16 lds[2][20480];

    const int tid = threadIdx.x;
    const int lane = tid & 63;
    const int w = tid >> 6;
    const int wr = w >> 1;
    const int wc = w & 1;
    const int l15 = lane & 15;
    const int l4 = lane >> 4;
    const int swz = ((l4 ^ (lane & 3)) * 8);
    const int sr = tid >> 2;
    const int sq = tid & 3;
    const int swzW = ((sq ^ (sr & 3)) * 8);

    for (int tile = blockIdx.x; tile < nTiles; tile += gridDim.x){
        const int mt = tile >> 4;
        const int cg = tile & 15;
        const int m0 = mt * 128;
        const int c0 = cg * 64;

        const int px0i = list[off + min(m0 + sr, count - 1)];
        const int px1i = list[off + min(m0 + 64 + sr, count - 1)];
        const float* px0 = ins + (size_t)px0i * 1024 + sq * 8;
        const float* px1 = ins + (size_t)px1i * 1024 + sq * 8;
        const float* ph0 = ys + (ptrdiff_t)(px0i - 128) * 1024 + sq * 8;
        const float* ph1 = ys + (ptrdiff_t)(px1i - 128) * 1024 + sq * 8;
        const u16* pb[6];
        #pragma unroll
        for (int pp = 0; pp < 6; ++pp){
            const int g = pp >> 1, m = pp & 1;
            const u16* W = m ? Wht : Wit;
            pb[pp] = W + (size_t)(g * 1024 + c0 + sr) * 1024 + sq * 8;
        }

        f32x4 acc[4][4][2];
        #pragma unroll
        for (int gi = 0; gi < 4; ++gi)
            #pragma unroll
            for (int rf = 0; rf < 4; ++rf)
                #pragma unroll
                for (int cf = 0; cf < 2; ++cf)
                    acc[gi][rf][cf] = (f32x4){0.f, 0.f, 0.f, 0.f};

        {
            u16* N = lds[0];
            *(u32x4*)&N[sr * 32 + swzW] = pack8(*(const f32x4*)(px0), *(const f32x4*)(px0 + 4));
            *(u32x4*)&N[(64 + sr) * 32 + swzW] = pack8(*(const f32x4*)(px1), *(const f32x4*)(px1 + 4));
            if (hasH){
                *(u32x4*)&N[(128 + sr) * 32 + swzW] = pack8(*(const f32x4*)(ph0), *(const f32x4*)(ph0 + 4));
                *(u32x4*)&N[(192 + sr) * 32 + swzW] = pack8(*(const f32x4*)(ph1), *(const f32x4*)(ph1 + 4));
            }
            #pragma unroll
            for (int pp = 0; pp < 6; ++pp)
                *(u32x4*)&N[8192 + (pp * 64 + sr) * 32 + swzW] = *(const u32x4*)(pb[pp]);
        }
        __syncthreads();

        int cur = 0;
        #pragma unroll 2
        for (int kt = 0; kt < 32; ++kt){
            f32x4 nx0a, nx0b, nx1a, nx1b, nh0a, nh0b, nh1a, nh1b;
            u32x4 sb[6];
            const bool more = (kt < 31);
            if (more){
                const int kof = (kt + 1) * 32;
                nx0a = *(const f32x4*)(px0 + kof); nx0b = *(const f32x4*)(px0 + kof + 4);
                nx1a = *(const f32x4*)(px1 + kof); nx1b = *(const f32x4*)(px1 + kof + 4);
                if (hasH){
                    nh0a = *(const f32x4*)(ph0 + kof); nh0b = *(const f32x4*)(ph0 + kof + 4);
                    nh1a = *(const f32x4*)(ph1 + kof); nh1b = *(const f32x4*)(ph1 + kof + 4);
                }
                #pragma unroll
                for (int pp = 0; pp < 6; ++pp) sb[pp] = *(const u32x4*)(pb[pp] + kof);
            }

            const u16* L = lds[cur];
            bf16x8 ax[4], ah[4];
            #pragma unroll
            for (int rf = 0; rf < 4; ++rf)
                ax[rf] = *(const bf16x8*)&L[(wr * 64 + rf * 16 + l15) * 32 + swz];
            if (hasH){
                #pragma unroll
                for (int rf = 0; rf < 4; ++rf)
                    ah[rf] = *(const bf16x8*)&L[(128 + wr * 64 + rf * 16 + l15) * 32 + swz];
            }
            #pragma unroll
            for (int g = 0; g < 3; ++g){
                #pragma unroll
                for (int cf = 0; cf < 2; ++cf){
                    const int brow = g * 128 + wc * 32 + cf * 16 + l15;
                    bf16x8 bv = *(const bf16x8*)&L[8192 + brow * 32 + swz];
                    const int gx = (g == 2) ? 2 : g;
                    #pragma unroll
                    for (int rf = 0; rf < 4; ++rf)
                        acc[gx][rf][cf] = __builtin_amdgcn_mfma_f32_16x16x32_bf16(
                            ax[rf], bv, acc[gx][rf][cf], 0, 0, 0);
                    if (hasH){
                        bf16x8 bh = *(const bf16x8*)&L[8192 + (brow + 64) * 32 + swz];
                        const int gh = (g == 2) ? 3 : g;
                        #pragma unroll
                        for (int rf = 0; rf < 4; ++rf)
                            acc[gh][rf][cf] = __builtin_amdgcn_mfma_f32_16x16x32_bf16(
                                ah[rf], bh, acc[gh][rf][cf], 0, 0, 0);
                    }
                }
            }

            if (more){
                u16* N = lds[cur ^ 1];
                *(u32x4*)&N[sr * 32 + swzW] = pack8(nx0a, nx0b);
                *(u32x4*)&N[(64 + sr) * 32 + swzW] = pack8(nx1a, nx1b);
                if (hasH){
                    *(u32x4*)&N[(128 + sr) * 32 + swzW] = pack8(nh0a, nh0b);
                    *(u32x4*)&N[(192 + sr) * 32 + swzW] = pack8(nh1a, nh1b);
                }
                #pragma unroll
                for (int pp = 0; pp < 6; ++pp)
                    *(u32x4*)&N[8192 + (pp * 64 + sr) * 32 + swzW] = sb[pp];
            }
            __syncthreads();
            cur ^= 1;
        }

        #pragma unroll
        for (int cf = 0; cf < 2; ++cf){
            const int colh = c0 + wc * 32 + cf * 16 + l15;
            const float b_r = bi[colh];
            const float b_z = bi[1024 + colh];
            const float b_n = bi[2048 + colh];
            const float b_h = bhn[colh];
            #pragma unroll
            for (int rf = 0; rf < 4; ++rf){
                #pragma unroll
                for (int m = 0; m < 4; ++m){
                    const int rloc = wr * 64 + rf * 16 + l4 * 4 + m;
                    const int p = list[off + min(m0 + rloc, count - 1)];
                    const float rr = 1.f / (1.f + __expf(-(acc[0][rf][cf][m] + b_r)));
                    const float zz = 1.f / (1.f + __expf(-(acc[1][rf][cf][m] + b_z)));
                    const float nn = tanhf(acc[2][rf][cf][m] + b_n + rr * (acc[3][rf][cf][m] + b_h));
                    float hp = 0.f;
                    if (hasH) hp = ys[(size_t)(p - 128) * 1024 + colh];
                    ys[(size_t)p * 1024 + colh] = (1.f - zz) * nn + zz * hp;
                }
            }
        }
    }
}

extern "C" void kernel_launch(void* const* d_in, const int* in_sizes, int n_in,
                              void* d_out, int out_size, void* d_ws, size_t ws_size,
                              hipStream_t stream)
{
    (void)in_sizes; (void)n_in; (void)out_size;
    const float* ins  = (const float*)d_in[0];
    const void*  rst  = d_in[1];
    const float* Wi   = (const float*)d_in[2];
    const float* bi   = (const float*)d_in[3];
    const float* Wh   = (const float*)d_in[4];
    const float* bhn  = (const float*)d_in[5];
    float* ys = (float*)d_out;
    u8* ws = (u8*)d_ws;

    const size_t A = 12648448;
    u16* Wit    = (u16*)(ws + 0);
    u16* Wht    = (u16*)(ws + 6291456);
    u8*  age    = ws + 12582912;           // 64 KB
    int* counts = (int*)(ws + A + 0);
    int* offs   = (int*)(ws + A + 256);
    int* gbase  = (int*)(ws + A + 512);
    int* tbase  = (int*)(ws + A + 768);
    u32* fin    = (u32*)(ws + A + 1024);   // 4 KB
    int* flag   = (int*)(ws + A + 5120);   // outside memset range
    int* bh     = (int*)(ws + A + 5376);
    int* bb     = (int*)(ws + A + 54528);
    u16* posof  = (u16*)(ws + A + 103680);
    u16* list   = (u16*)(ws + A + 234752);
    u16* insbf  = (u16*)(ws + 13014272);   // Mrows*2KB (aliased as hbf after k_xi)

    int bw = 0, bwlog = 0;
    {
        const size_t base = 13014272;
        if (ws_size >= base + (size_t)TT * 128 * 8192)      { bw = 128; bwlog = 7; }
        else if (ws_size >= base + (size_t)TT * 64 * 8192)  { bw = 64;  bwlog = 6; }
        else if (ws_size >= base + (size_t)TT * 32 * 8192)  { bw = 32;  bwlog = 5; }
    }

    k_detect<<<1, 256, 0, stream>>>((const u8*)rst, flag);
    k_packT<<<dim3(32, 96, 2), dim3(32, 8), 0, stream>>>(Wi, Wh, Wit, Wht);

    if (bw == 0){
        const int Mr = TT * BB, NB = Mr / 256;
        hipMemsetAsync(ws + A, 0, 5120, stream);
        k_ages<<<NB, 256, 0, stream>>>(rst, flag, 0, 7, age, bh);
        k_offsets<<<1, 64, 0, stream>>>(bh, NB, counts, offs, gbase, tbase, bb);
        k_scatter<<<NB, 256, 0, stream>>>(age, offs, bb, list, posof);
        for (int it = 0; it < NITER; ++it)
            k_scan_fb<<<512, 256, 0, stream>>>(it, list, offs, counts, ins, ys, Wit, Wht, bi, bhn);
        return;
    }

    u16* xi = insbf + (size_t)TT * bw * 1024;
    u16* hbf = insbf;                      // alias: insbf fully consumed by k_xi first
    const int nch = BB / bw;
    const int Mrows = TT * bw;
    const int NB = Mrows / 256;

    for (int c = 0; c < nch; ++c){
        const int b0 = c * bw;
        hipMemsetAsync(ws + A, 0, 5120, stream);   // counts/offs/gbase/tbase/fin
        k_ages<<<NB, 256, 0, stream>>>(rst, flag, b0, bwlog, age, bh);
        k_offsets<<<1, 64, 0, stream>>>(bh, NB, counts, offs, gbase, tbase, bb);
        k_scatter<<<NB, 256, 0, stream>>>(age, offs, bb, list, posof);
        k_tobf<<<2048, 256, 0, stream>>>(ins, insbf, b0, bwlog, Mrows * 128);
        k_xi<<<3072, 256, 0, stream>>>(insbf, Wit, xi, Mrows);
        k_h0<<<2048, 256, 0, stream>>>(list, counts, xi, ys, hbf, bi, bhn, b0, bwlog);
        for (int it = 1; it < ASTART; ++it){
            int est = ((Mrows >> (it + 1)) / 128 + 1) * 16;
            int grid = est < 32 ? 32 : (est > 512 ? 512 : est);
            k_scanh<<<grid, 256, 0, stream>>>(it, list, offs, counts, posof, hbf, xi,
                                              ys, Wht, bi, bhn, b0, bwlog);
        }
        k_scan_all<<<512, 256, 0, stream>>>(list, offs, counts, posof, hbf, xi, ys,
                                            Wht, bi, bhn, b0, bwlog, gbase, tbase,
                                            fin, ASTART);
    }
}